// Round 1
// baseline (3340.385 us; speedup 1.0000x reference)
//
#include <hip/hip_runtime.h>
#include <cstdint>
#include <cstddef>

typedef unsigned short u16;
typedef __attribute__((ext_vector_type(8))) short short8;
typedef __attribute__((ext_vector_type(4))) float f32x4;

#define BB 16
#define NT 1569
#define DIM 768
#define NH 12
#define HD 64
#define FR 8
#define NS 196
#define MROWS (BB*NT)   // 25104

__device__ __forceinline__ float bf2f(u16 h) {
    return __uint_as_float(((unsigned int)h) << 16);
}
__device__ __forceinline__ u16 f2bf(float f) {
    unsigned int u = __float_as_uint(f);
    u += 0x7fff + ((u >> 16) & 1);   // RNE
    return (u16)(u >> 16);
}

// ---------------- LayerNorm: fp32 in -> bf16 out ----------------
__global__ __launch_bounds__(256) void ln_kernel(const float* __restrict__ x,
        const float* __restrict__ w, const float* __restrict__ b,
        u16* __restrict__ out) {
    int row = blockIdx.x;
    size_t base = (size_t)row * DIM;
    int tid = threadIdx.x;
    float v0 = x[base + tid];
    float v1 = x[base + tid + 256];
    float v2 = x[base + tid + 512];
    float s = v0 + v1 + v2;
    float q = v0*v0 + v1*v1 + v2*v2;
    #pragma unroll
    for (int o = 32; o >= 1; o >>= 1) {
        s += __shfl_xor(s, o, 64);
        q += __shfl_xor(q, o, 64);
    }
    __shared__ float rs[4], rq[4];
    int wave = tid >> 6, lane = tid & 63;
    if (lane == 0) { rs[wave] = s; rq[wave] = q; }
    __syncthreads();
    float S = rs[0]+rs[1]+rs[2]+rs[3];
    float Q = rq[0]+rq[1]+rq[2]+rq[3];
    float mean = S * (1.0f/DIM);
    float var  = Q * (1.0f/DIM) - mean*mean;
    float inv  = rsqrtf(var + 1e-6f);
    out[base+tid]     = f2bf((v0-mean)*inv*w[tid]     + b[tid]);
    out[base+tid+256] = f2bf((v1-mean)*inv*w[tid+256] + b[tid+256]);
    out[base+tid+512] = f2bf((v2-mean)*inv*w[tid+512] + b[tid+512]);
}

// ------------- weight convert: fp32 [K,N] -> bf16 [N,K] -------------
__global__ __launch_bounds__(256) void wconv_kernel(const float* __restrict__ in,
        u16* __restrict__ out, int K, int N) {
    __shared__ float tile[32][33];
    int n0 = blockIdx.x * 32, k0 = blockIdx.y * 32;
    int tx = threadIdx.x & 31, ty = threadIdx.x >> 5;
    #pragma unroll
    for (int i = 0; i < 32; i += 8)
        tile[ty+i][tx] = in[(size_t)(k0+ty+i)*N + n0+tx];
    __syncthreads();
    #pragma unroll
    for (int i = 0; i < 32; i += 8)
        out[(size_t)(n0+ty+i)*K + k0+tx] = f2bf(tile[tx][ty+i]);
}

// ---------------- bf16 MFMA GEMM: C = A[M,K] * BT[N,K]^T ----------------
// EPI: 0 = +bias, 1 = +bias+residual, 2 = +bias+gelu. OBF: bf16 out else fp32.
template<int EPI, bool OBF>
__global__ __launch_bounds__(256) void gemm_kernel(
        const u16* __restrict__ A, const u16* __restrict__ BT,
        const float* __restrict__ bias, const float* __restrict__ resid,
        void* __restrict__ Cout, int M, int N, int K) {
    __shared__ u16 lsA[128*40];   // padded stride 40 (80B, 16B-aligned rows)
    __shared__ u16 lsB[128*40];
    int tid = threadIdx.x;
    int row0 = blockIdx.x * 128, col0 = blockIdx.y * 128;
    int wave = tid >> 6, lane = tid & 63;
    int wm = (wave >> 1) * 64, wn = (wave & 1) * 64;
    int lrow = lane & 15, quad = lane >> 4;
    f32x4 acc[4][4] = {};
    for (int k0 = 0; k0 < K; k0 += 32) {
        #pragma unroll
        for (int i = 0; i < 2; ++i) {
            int c = tid + i*256;
            int r = c >> 2, c8 = (c & 3) * 8;
            int gr = row0 + r; if (gr > M-1) gr = M-1;   // clamp; stores guarded
            *(short8*)&lsA[r*40 + c8] = *(const short8*)(A + (size_t)gr*K + k0 + c8);
            *(short8*)&lsB[r*40 + c8] = *(const short8*)(BT + (size_t)(col0+r)*K + k0 + c8);
        }
        __syncthreads();
        short8 af[4], bfr[4];
        #pragma unroll
        for (int t = 0; t < 4; ++t)
            af[t] = *(const short8*)&lsA[(wm + t*16 + lrow)*40 + quad*8];
        #pragma unroll
        for (int t = 0; t < 4; ++t)
            bfr[t] = *(const short8*)&lsB[(wn + t*16 + lrow)*40 + quad*8];
        #pragma unroll
        for (int i = 0; i < 4; ++i)
            #pragma unroll
            for (int j = 0; j < 4; ++j)
                acc[i][j] = __builtin_amdgcn_mfma_f32_16x16x32_bf16(af[i], bfr[j], acc[i][j], 0, 0, 0);
        __syncthreads();
    }
    #pragma unroll
    for (int i = 0; i < 4; ++i) {
      #pragma unroll
      for (int j = 0; j < 4; ++j) {
        int gn = col0 + wn + j*16 + lrow;
        float bv = bias[gn];
        #pragma unroll
        for (int r = 0; r < 4; ++r) {
            int gm = row0 + wm + i*16 + quad*4 + r;
            if (gm < M) {
                float v = acc[i][j][r] + bv;
                if (EPI == 1) v += resid[(size_t)gm*N + gn];
                if (EPI == 2) {
                    float z = 0.7978845608028654f*(v + 0.044715f*v*v*v);
                    float t = 1.0f - 2.0f/(__expf(2.0f*z) + 1.0f);   // tanh(z)
                    v = 0.5f*v*(1.0f + t);
                }
                if (OBF) ((u16*)Cout)[(size_t)gm*N + gn] = f2bf(v);
                else     ((float*)Cout)[(size_t)gm*N + gn] = v;
            }
        }
      }
    }
}

// ------------- cls-token global attention: one block per (b,h) -------------
__global__ __launch_bounds__(256) void attn_cls_kernel(const u16* __restrict__ qkv,
        u16* __restrict__ out) {
    __shared__ float s[NT];
    __shared__ float qf[64];
    __shared__ float part[4][64];
    __shared__ float red[4];
    int b = blockIdx.x / NH, h = blockIdx.x % NH;
    size_t base = ((size_t)b*NT)*(3*DIM) + h*HD;
    int tid = threadIdx.x;
    if (tid < 64) qf[tid] = bf2f(qkv[base + tid]);
    __syncthreads();
    float lmax = -1e30f;
    for (int t = tid; t < NT; t += 256) {
        const u16* kp = qkv + base + (size_t)t*(3*DIM) + DIM;
        float a0=0,a1=0,a2=0,a3=0;
        #pragma unroll
        for (int d = 0; d < 64; d += 4) {
            a0 += qf[d]  *bf2f(kp[d]);
            a1 += qf[d+1]*bf2f(kp[d+1]);
            a2 += qf[d+2]*bf2f(kp[d+2]);
            a3 += qf[d+3]*bf2f(kp[d+3]);
        }
        float sc = (a0+a1+a2+a3)*0.125f;
        s[t] = sc;
        lmax = fmaxf(lmax, sc);
    }
    #pragma unroll
    for (int o = 32; o >= 1; o >>= 1) lmax = fmaxf(lmax, __shfl_xor(lmax, o, 64));
    if ((tid&63) == 0) red[tid>>6] = lmax;
    __syncthreads();
    float m = fmaxf(fmaxf(red[0],red[1]), fmaxf(red[2],red[3]));
    float lsum = 0.f;
    for (int t = tid; t < NT; t += 256) { float e = __expf(s[t]-m); s[t] = e; lsum += e; }
    #pragma unroll
    for (int o = 32; o >= 1; o >>= 1) lsum += __shfl_xor(lsum, o, 64);
    __syncthreads();                      // s[] writes + red reuse
    if ((tid&63) == 0) red[tid>>6] = lsum;
    __syncthreads();
    float inv = 1.0f/(red[0]+red[1]+red[2]+red[3]);
    int d = tid & 63, g = tid >> 6;
    float a = 0.f;
    for (int t = g; t < NT; t += 4)
        a += s[t]*bf2f(qkv[base + (size_t)t*(3*DIM) + 2*DIM + d]);
    part[g][d] = a;
    __syncthreads();
    if (tid < 64) {
        float o = (part[0][tid]+part[1][tid]+part[2][tid]+part[3][tid])*inv;
        out[((size_t)b*NT)*DIM + h*HD + tid] = f2bf(o);
    }
}

// ------------- time attention: one block per (b,h,n); 8 q x 9 kv -------------
__global__ __launch_bounds__(256) void attn_time_kernel(const u16* __restrict__ qkv,
        u16* __restrict__ out) {
    __shared__ float qs[8][68], ks[9][68], vs[9][68];
    __shared__ float pr[8][12];
    int bid = blockIdx.x;
    int n = bid % NS; int rem = bid / NS; int h = rem % NH; int b = rem / NH;
    size_t base = ((size_t)b*NT)*(3*DIM) + h*HD;
    int tid = threadIdx.x;
    for (int idx = tid; idx < 512; idx += 256) {
        int f = idx >> 6, d = idx & 63;
        int tok = 1 + f*NS + n;
        size_t p = base + (size_t)tok*(3*DIM) + d;
        qs[f][d]   = bf2f(qkv[p]);
        ks[f+1][d] = bf2f(qkv[p + DIM]);
        vs[f+1][d] = bf2f(qkv[p + 2*DIM]);
    }
    if (tid < 64) {
        ks[0][tid] = bf2f(qkv[base + DIM + tid]);
        vs[0][tid] = bf2f(qkv[base + 2*DIM + tid]);
    }
    __syncthreads();
    if (tid < 72) {
        int fq = tid / 9, kk = tid % 9;
        float a0=0,a1=0,a2=0,a3=0;
        #pragma unroll
        for (int d = 0; d < 64; d += 4) {
            a0 += qs[fq][d]  *ks[kk][d];
            a1 += qs[fq][d+1]*ks[kk][d+1];
            a2 += qs[fq][d+2]*ks[kk][d+2];
            a3 += qs[fq][d+3]*ks[kk][d+3];
        }
        pr[fq][kk] = (a0+a1+a2+a3)*0.125f;
    }
    __syncthreads();
    if (tid < 8) {
        float m = -1e30f;
        #pragma unroll
        for (int kk = 0; kk < 9; ++kk) m = fmaxf(m, pr[tid][kk]);
        float sum = 0.f;
        #pragma unroll
        for (int kk = 0; kk < 9; ++kk) { float e = __expf(pr[tid][kk]-m); pr[tid][kk] = e; sum += e; }
        float inv = 1.0f/sum;
        #pragma unroll
        for (int kk = 0; kk < 9; ++kk) pr[tid][kk] *= inv;
    }
    __syncthreads();
    for (int idx = tid; idx < 512; idx += 256) {
        int fq = idx >> 6, d = idx & 63;
        float a = 0.f;
        #pragma unroll
        for (int kk = 0; kk < 9; ++kk) a += pr[fq][kk]*vs[kk][d];
        int tok = 1 + fq*NS + n;
        out[((size_t)b*NT + tok)*DIM + h*HD + d] = f2bf(a);
    }
}

// ------------- space attention: one block per (b,h,f); 196 q x 197 kv -------------
#define NKEY 197
__global__ __launch_bounds__(256) void attn_space_kernel(const u16* __restrict__ qkv,
        u16* __restrict__ out) {
    __shared__ u16  KT[64*200];     // KT[d*200 + key]
    __shared__ u16  V [NKEY*64];    // V[key*64 + d]
    __shared__ float parr[4][200];
    __shared__ float qbuf[4][64];
    int bid = blockIdx.x;
    int b = bid / (NH*FR); int rem = bid % (NH*FR); int h = rem / FR; int f = rem % FR;
    size_t base = ((size_t)b*NT)*(3*DIM) + h*HD;
    int tid = threadIdx.x;
    for (int idx = tid; idx < NKEY*64; idx += 256) {
        int key = idx >> 6, d = idx & 63;
        int tok = (key == 0) ? 0 : (1 + f*NS + (key-1));
        size_t p = base + (size_t)tok*(3*DIM) + d;
        KT[d*200 + key] = qkv[p + DIM];
        V[idx]          = qkv[p + 2*DIM];
    }
    __syncthreads();
    int wave = tid >> 6, lane = tid & 63;
    for (int qi = wave; qi < NS; qi += 4) {         // 196/4 = 49: uniform
        int qtok = 1 + f*NS + qi;
        qbuf[wave][lane] = bf2f(qkv[base + (size_t)qtok*(3*DIM) + lane]);
        __syncthreads();
        float s[4];
        #pragma unroll
        for (int c = 0; c < 4; ++c) {
            int key = c*64 + lane;
            float a0=0,a1=0,a2=0,a3=0;
            if (key < NKEY) {
                #pragma unroll
                for (int d = 0; d < 64; d += 4) {
                    a0 += qbuf[wave][d]  *bf2f(KT[(d)*200+key]);
                    a1 += qbuf[wave][d+1]*bf2f(KT[(d+1)*200+key]);
                    a2 += qbuf[wave][d+2]*bf2f(KT[(d+2)*200+key]);
                    a3 += qbuf[wave][d+3]*bf2f(KT[(d+3)*200+key]);
                }
            }
            s[c] = (key < NKEY) ? (a0+a1+a2+a3)*0.125f : -1e30f;
        }
        float m = fmaxf(fmaxf(s[0],s[1]), fmaxf(s[2],s[3]));
        #pragma unroll
        for (int o = 32; o >= 1; o >>= 1) m = fmaxf(m, __shfl_xor(m, o, 64));
        float e[4], sum = 0.f;
        #pragma unroll
        for (int c = 0; c < 4; ++c) {
            int key = c*64 + lane;
            e[c] = (key < NKEY) ? __expf(s[c]-m) : 0.f;
            sum += e[c];
        }
        #pragma unroll
        for (int o = 32; o >= 1; o >>= 1) sum += __shfl_xor(sum, o, 64);
        float inv = 1.0f/sum;
        #pragma unroll
        for (int c = 0; c < 4; ++c) {
            int key = c*64 + lane;
            if (key < NKEY) parr[wave][key] = e[c]*inv;
        }
        __syncthreads();
        int d = lane;
        float a0=0,a1=0,a2=0,a3=0;
        for (int key = 0; key < 196; key += 4) {
            a0 += parr[wave][key]  *bf2f(V[(key)*64+d]);
            a1 += parr[wave][key+1]*bf2f(V[(key+1)*64+d]);
            a2 += parr[wave][key+2]*bf2f(V[(key+2)*64+d]);
            a3 += parr[wave][key+3]*bf2f(V[(key+3)*64+d]);
        }
        a0 += parr[wave][196]*bf2f(V[196*64+d]);
        out[((size_t)b*NT + qtok)*DIM + h*HD + d] = f2bf(a0+a1+a2+a3);
    }
}

// ---------------------------------------------------------------------------
extern "C" void kernel_launch(void* const* d_in, const int* in_sizes, int n_in,
                              void* d_out, int out_size, void* d_ws, size_t ws_size,
                              hipStream_t stream) {
    const float* x          = (const float*)d_in[0];
    const float* norm1_w    = (const float*)d_in[1];
    const float* norm1_b    = (const float*)d_in[2];
    const float* norm2_w    = (const float*)d_in[3];
    const float* norm2_b    = (const float*)d_in[4];
    const float* norm3_w    = (const float*)d_in[5];
    const float* norm3_b    = (const float*)d_in[6];
    const float* t_qkv_w    = (const float*)d_in[7];
    const float* t_qkv_b    = (const float*)d_in[8];
    const float* t_proj_w   = (const float*)d_in[9];
    const float* t_proj_b   = (const float*)d_in[10];
    const float* s_qkv_w    = (const float*)d_in[11];
    const float* s_qkv_b    = (const float*)d_in[12];
    const float* s_proj_w   = (const float*)d_in[13];
    const float* s_proj_b   = (const float*)d_in[14];
    const float* mlp_w1     = (const float*)d_in[15];
    const float* mlp_b1     = (const float*)d_in[16];
    const float* mlp_w2     = (const float*)d_in[17];
    const float* mlp_b2     = (const float*)d_in[18];
    float* out = (float*)d_out;

    // workspace layout (bytes)
    char* ws = (char*)d_ws;
    const size_t M = MROWS;
    u16*  qkv  = (u16*)(ws);                          // M*2304 bf16
    u16*  attn = (u16*)(ws + M*2304*2);               // M*768 bf16
    u16*  hbuf = (u16*)(ws);                          // M*3072 bf16 (overlays qkv+attn)
    u16*  xn   = (u16*)(ws + M*3072*2);               // M*768 bf16
    float* x1  = (float*)(ws + M*3072*2 + M*768*2);   // M*768 fp32
    char* wsp  = ws + M*3072*2 + M*768*2 + M*768*4;
    u16* wqT_t = (u16*)(wsp);                 wsp += 2304*768*2;
    u16* wqT_s = (u16*)(wsp);                 wsp += 2304*768*2;
    u16* wpT_t = (u16*)(wsp);                 wsp += 768*768*2;
    u16* wpT_s = (u16*)(wsp);                 wsp += 768*768*2;
    u16* w1T   = (u16*)(wsp);                 wsp += 3072*768*2;
    u16* w2T   = (u16*)(wsp);

    // ---- weight conversion (transpose to [N,K] bf16) ----
    wconv_kernel<<<dim3(2304/32, 768/32), 256, 0, stream>>>(t_qkv_w, wqT_t, 768, 2304);
    wconv_kernel<<<dim3(2304/32, 768/32), 256, 0, stream>>>(s_qkv_w, wqT_s, 768, 2304);
    wconv_kernel<<<dim3(768/32, 768/32), 256, 0, stream>>>(t_proj_w, wpT_t, 768, 768);
    wconv_kernel<<<dim3(768/32, 768/32), 256, 0, stream>>>(s_proj_w, wpT_s, 768, 768);
    wconv_kernel<<<dim3(3072/32, 768/32), 256, 0, stream>>>(mlp_w1, w1T, 768, 3072);
    wconv_kernel<<<dim3(768/32, 3072/32), 256, 0, stream>>>(mlp_w2, w2T, 3072, 768);

    const int GM = (MROWS + 127) / 128;   // 197

    // ---- time attention branch ----
    ln_kernel<<<MROWS, 256, 0, stream>>>(x, norm3_w, norm3_b, xn);
    gemm_kernel<0, true ><<<dim3(GM, 2304/128), 256, 0, stream>>>(xn, wqT_t, t_qkv_b, nullptr, qkv, MROWS, 2304, 768);
    attn_cls_kernel <<<BB*NH, 256, 0, stream>>>(qkv, attn);
    attn_time_kernel<<<BB*NH*NS, 256, 0, stream>>>(qkv, attn);
    gemm_kernel<1, false><<<dim3(GM, 768/128), 256, 0, stream>>>(attn, wpT_t, t_proj_b, x, x1, MROWS, 768, 768);

    // ---- space attention branch ----
    ln_kernel<<<MROWS, 256, 0, stream>>>(x1, norm1_w, norm1_b, xn);
    gemm_kernel<0, true ><<<dim3(GM, 2304/128), 256, 0, stream>>>(xn, wqT_s, s_qkv_b, nullptr, qkv, MROWS, 2304, 768);
    attn_cls_kernel  <<<BB*NH, 256, 0, stream>>>(qkv, attn);
    attn_space_kernel<<<BB*NH*FR, 256, 0, stream>>>(qkv, attn);
    gemm_kernel<1, false><<<dim3(GM, 768/128), 256, 0, stream>>>(attn, wpT_s, s_proj_b, x1, out, MROWS, 768, 768);

    // ---- MLP ----
    ln_kernel<<<MROWS, 256, 0, stream>>>(out, norm2_w, norm2_b, xn);
    gemm_kernel<2, true ><<<dim3(GM, 3072/128), 256, 0, stream>>>(xn, w1T, mlp_b1, nullptr, hbuf, MROWS, 3072, 768);
    gemm_kernel<1, false><<<dim3(GM, 768/128), 256, 0, stream>>>(hbuf, w2T, mlp_b2, out, out, MROWS, 768, 3072);
}

// Round 2
// 1744.967 us; speedup vs baseline: 1.9143x; 1.9143x over previous
//
#include <hip/hip_runtime.h>
#include <cstdint>
#include <cstddef>

typedef unsigned short u16;
typedef __attribute__((ext_vector_type(8))) short short8;
typedef __attribute__((ext_vector_type(4))) float f32x4;

#define BB 16
#define NT 1569
#define DIM 768
#define NH 12
#define HD 64
#define FR 8
#define NS 196
#define MROWS (BB*NT)   // 25104
#define NKEY 197

__device__ __forceinline__ float bf2f(u16 h) {
    return __uint_as_float(((unsigned int)h) << 16);
}
__device__ __forceinline__ u16 f2bf(float f) {
    unsigned int u = __float_as_uint(f);
    u += 0x7fff + ((u >> 16) & 1);   // RNE
    return (u16)(u >> 16);
}

// ---------------- LayerNorm: fp32 in -> bf16 out ----------------
__global__ __launch_bounds__(256) void ln_kernel(const float* __restrict__ x,
        const float* __restrict__ w, const float* __restrict__ b,
        u16* __restrict__ out) {
    int row = blockIdx.x;
    size_t base = (size_t)row * DIM;
    int tid = threadIdx.x;
    float v0 = x[base + tid];
    float v1 = x[base + tid + 256];
    float v2 = x[base + tid + 512];
    float s = v0 + v1 + v2;
    float q = v0*v0 + v1*v1 + v2*v2;
    #pragma unroll
    for (int o = 32; o >= 1; o >>= 1) {
        s += __shfl_xor(s, o, 64);
        q += __shfl_xor(q, o, 64);
    }
    __shared__ float rs[4], rq[4];
    int wave = tid >> 6, lane = tid & 63;
    if (lane == 0) { rs[wave] = s; rq[wave] = q; }
    __syncthreads();
    float S = rs[0]+rs[1]+rs[2]+rs[3];
    float Q = rq[0]+rq[1]+rq[2]+rq[3];
    float mean = S * (1.0f/DIM);
    float var  = Q * (1.0f/DIM) - mean*mean;
    float inv  = rsqrtf(var + 1e-6f);
    out[base+tid]     = f2bf((v0-mean)*inv*w[tid]     + b[tid]);
    out[base+tid+256] = f2bf((v1-mean)*inv*w[tid+256] + b[tid+256]);
    out[base+tid+512] = f2bf((v2-mean)*inv*w[tid+512] + b[tid+512]);
}

// ------------- weight convert: fp32 [K,N] -> bf16 [N,K] -------------
__global__ __launch_bounds__(256) void wconv_kernel(const float* __restrict__ in,
        u16* __restrict__ out, int K, int N) {
    __shared__ float tile[32][33];
    int n0 = blockIdx.x * 32, k0 = blockIdx.y * 32;
    int tx = threadIdx.x & 31, ty = threadIdx.x >> 5;
    #pragma unroll
    for (int i = 0; i < 32; i += 8)
        tile[ty+i][tx] = in[(size_t)(k0+ty+i)*N + n0+tx];
    __syncthreads();
    #pragma unroll
    for (int i = 0; i < 32; i += 8)
        out[(size_t)(n0+ty+i)*K + k0+tx] = f2bf(tile[tx][ty+i]);
}

// ---------------- bf16 MFMA GEMM: C = A[M,K] * BT[N,K]^T ----------------
// EPI: 0 = +bias, 1 = +bias+residual, 2 = +bias+gelu. OBF: bf16 out else fp32.
template<int EPI, bool OBF>
__global__ __launch_bounds__(256) void gemm_kernel(
        const u16* __restrict__ A, const u16* __restrict__ BT,
        const float* __restrict__ bias, const float* __restrict__ resid,
        void* __restrict__ Cout, int M, int N, int K) {
    __shared__ u16 lsA[128*40];   // padded stride 40 (80B, 16B-aligned rows)
    __shared__ u16 lsB[128*40];
    int tid = threadIdx.x;
    int row0 = blockIdx.x * 128, col0 = blockIdx.y * 128;
    int wave = tid >> 6, lane = tid & 63;
    int wm = (wave >> 1) * 64, wn = (wave & 1) * 64;
    int lrow = lane & 15, quad = lane >> 4;
    f32x4 acc[4][4] = {};
    for (int k0 = 0; k0 < K; k0 += 32) {
        #pragma unroll
        for (int i = 0; i < 2; ++i) {
            int c = tid + i*256;
            int r = c >> 2, c8 = (c & 3) * 8;
            int gr = row0 + r; if (gr > M-1) gr = M-1;   // clamp; stores guarded
            *(short8*)&lsA[r*40 + c8] = *(const short8*)(A + (size_t)gr*K + k0 + c8);
            *(short8*)&lsB[r*40 + c8] = *(const short8*)(BT + (size_t)(col0+r)*K + k0 + c8);
        }
        __syncthreads();
        short8 af[4], bfr[4];
        #pragma unroll
        for (int t = 0; t < 4; ++t)
            af[t] = *(const short8*)&lsA[(wm + t*16 + lrow)*40 + quad*8];
        #pragma unroll
        for (int t = 0; t < 4; ++t)
            bfr[t] = *(const short8*)&lsB[(wn + t*16 + lrow)*40 + quad*8];
        #pragma unroll
        for (int i = 0; i < 4; ++i)
            #pragma unroll
            for (int j = 0; j < 4; ++j)
                acc[i][j] = __builtin_amdgcn_mfma_f32_16x16x32_bf16(af[i], bfr[j], acc[i][j], 0, 0, 0);
        __syncthreads();
    }
    #pragma unroll
    for (int i = 0; i < 4; ++i) {
      #pragma unroll
      for (int j = 0; j < 4; ++j) {
        int gn = col0 + wn + j*16 + lrow;
        float bv = bias[gn];
        #pragma unroll
        for (int r = 0; r < 4; ++r) {
            int gm = row0 + wm + i*16 + quad*4 + r;
            if (gm < M) {
                float v = acc[i][j][r] + bv;
                if (EPI == 1) v += resid[(size_t)gm*N + gn];
                if (EPI == 2) {
                    float z = 0.7978845608028654f*(v + 0.044715f*v*v*v);
                    float t = 1.0f - 2.0f/(__expf(2.0f*z) + 1.0f);   // tanh(z)
                    v = 0.5f*v*(1.0f + t);
                }
                if (OBF) ((u16*)Cout)[(size_t)gm*N + gn] = f2bf(v);
                else     ((float*)Cout)[(size_t)gm*N + gn] = v;
            }
        }
      }
    }
}

// ------------- cls-token global attention: one block per (b,h) -------------
__global__ __launch_bounds__(256) void attn_cls_kernel(const u16* __restrict__ qkv,
        u16* __restrict__ out) {
    __shared__ float s[NT];
    __shared__ float qf[64];
    __shared__ float part[4][64];
    __shared__ float red[4];
    int b = blockIdx.x / NH, h = blockIdx.x % NH;
    size_t base = ((size_t)b*NT)*(3*DIM) + h*HD;
    int tid = threadIdx.x;
    if (tid < 64) qf[tid] = bf2f(qkv[base + tid]);
    __syncthreads();
    float lmax = -1e30f;
    for (int t = tid; t < NT; t += 256) {
        const u16* kp = qkv + base + (size_t)t*(3*DIM) + DIM;
        float a0=0,a1=0,a2=0,a3=0;
        #pragma unroll
        for (int d = 0; d < 64; d += 4) {
            a0 += qf[d]  *bf2f(kp[d]);
            a1 += qf[d+1]*bf2f(kp[d+1]);
            a2 += qf[d+2]*bf2f(kp[d+2]);
            a3 += qf[d+3]*bf2f(kp[d+3]);
        }
        float sc = (a0+a1+a2+a3)*0.125f;
        s[t] = sc;
        lmax = fmaxf(lmax, sc);
    }
    #pragma unroll
    for (int o = 32; o >= 1; o >>= 1) lmax = fmaxf(lmax, __shfl_xor(lmax, o, 64));
    if ((tid&63) == 0) red[tid>>6] = lmax;
    __syncthreads();
    float m = fmaxf(fmaxf(red[0],red[1]), fmaxf(red[2],red[3]));
    float lsum = 0.f;
    for (int t = tid; t < NT; t += 256) { float e = __expf(s[t]-m); s[t] = e; lsum += e; }
    #pragma unroll
    for (int o = 32; o >= 1; o >>= 1) lsum += __shfl_xor(lsum, o, 64);
    __syncthreads();                      // s[] writes + red reuse
    if ((tid&63) == 0) red[tid>>6] = lsum;
    __syncthreads();
    float inv = 1.0f/(red[0]+red[1]+red[2]+red[3]);
    int d = tid & 63, g = tid >> 6;
    float a = 0.f;
    for (int t = g; t < NT; t += 4)
        a += s[t]*bf2f(qkv[base + (size_t)t*(3*DIM) + 2*DIM + d]);
    part[g][d] = a;
    __syncthreads();
    if (tid < 64) {
        float o = (part[0][tid]+part[1][tid]+part[2][tid]+part[3][tid])*inv;
        out[((size_t)b*NT)*DIM + h*HD + tid] = f2bf(o);
    }
}

// ------------- time attention: one block per (b,h,n); 8 q x 9 kv -------------
__global__ __launch_bounds__(256) void attn_time_kernel(const u16* __restrict__ qkv,
        u16* __restrict__ out) {
    __shared__ float qs[8][68], ks[9][68], vs[9][68];
    __shared__ float pr[8][12];
    int bid = blockIdx.x;
    int n = bid % NS; int rem = bid / NS; int h = rem % NH; int b = rem / NH;
    size_t base = ((size_t)b*NT)*(3*DIM) + h*HD;
    int tid = threadIdx.x;
    for (int idx = tid; idx < 512; idx += 256) {
        int f = idx >> 6, d = idx & 63;
        int tok = 1 + f*NS + n;
        size_t p = base + (size_t)tok*(3*DIM) + d;
        qs[f][d]   = bf2f(qkv[p]);
        ks[f+1][d] = bf2f(qkv[p + DIM]);
        vs[f+1][d] = bf2f(qkv[p + 2*DIM]);
    }
    if (tid < 64) {
        ks[0][tid] = bf2f(qkv[base + DIM + tid]);
        vs[0][tid] = bf2f(qkv[base + 2*DIM + tid]);
    }
    __syncthreads();
    if (tid < 72) {
        int fq = tid / 9, kk = tid % 9;
        float a0=0,a1=0,a2=0,a3=0;
        #pragma unroll
        for (int d = 0; d < 64; d += 4) {
            a0 += qs[fq][d]  *ks[kk][d];
            a1 += qs[fq][d+1]*ks[kk][d+1];
            a2 += qs[fq][d+2]*ks[kk][d+2];
            a3 += qs[fq][d+3]*ks[kk][d+3];
        }
        pr[fq][kk] = (a0+a1+a2+a3)*0.125f;
    }
    __syncthreads();
    if (tid < 8) {
        float m = -1e30f;
        #pragma unroll
        for (int kk = 0; kk < 9; ++kk) m = fmaxf(m, pr[tid][kk]);
        float sum = 0.f;
        #pragma unroll
        for (int kk = 0; kk < 9; ++kk) { float e = __expf(pr[tid][kk]-m); pr[tid][kk] = e; sum += e; }
        float inv = 1.0f/sum;
        #pragma unroll
        for (int kk = 0; kk < 9; ++kk) pr[tid][kk] *= inv;
    }
    __syncthreads();
    for (int idx = tid; idx < 512; idx += 256) {
        int fq = idx >> 6, d = idx & 63;
        float a = 0.f;
        #pragma unroll
        for (int kk = 0; kk < 9; ++kk) a += pr[fq][kk]*vs[kk][d];
        int tok = 1 + fq*NS + n;
        out[((size_t)b*NT + tok)*DIM + h*HD + d] = f2bf(a);
    }
}

// ------------- space attention (MFMA): one block per (b,h,f) -------------
// S = Q[196x64] K^T -> softmax -> O = P V.  Q,K fragments direct from global
// (block's K = 25 KB, L1-resident).  V staged transposed VT[d][key] in LDS;
// per-wave unnormalized-P bf16 buffer; 1/rowsum folded into epilogue.
// LDS = 64*232*2 + 4*16*232*2 = 59392 B -> 2 blocks/CU.
#define VSTR 232
__global__ __launch_bounds__(256, 2) void attn_space_kernel(const u16* __restrict__ qkv,
        u16* __restrict__ out) {
    __shared__ u16 VT[64*VSTR];        // [d][key], cols 197..231 zero
    __shared__ u16 Ps[4][16*VSTR];     // per-wave P[qrow][key], cols 208..231 zero
    int bid = blockIdx.x;
    int b = bid / (NH*FR); int rem = bid % (NH*FR); int h = rem / FR; int f = rem % FR;
    size_t base = ((size_t)b*NT)*(3*DIM) + (size_t)h*HD;
    int tid = threadIdx.x;
    int wave = tid >> 6, lane = tid & 63;
    int cb = lane & 15, quad = lane >> 4;

    // stage V transposed: consecutive lanes -> consecutive keys (LDS conflict-free)
    for (int idx = tid; idx < NKEY*64; idx += 256) {
        int d = idx / NKEY, key = idx - d*NKEY;
        int tok = (key == 0) ? 0 : (1 + f*NS + key - 1);
        VT[d*VSTR + key] = qkv[base + (size_t)tok*(3*DIM) + 2*DIM + d];
    }
    for (int idx = tid; idx < 64*(VSTR-NKEY); idx += 256) {
        int d = idx / (VSTR-NKEY), c = idx - d*(VSTR-NKEY);
        VT[d*VSTR + NKEY + c] = 0;
    }
    for (int idx = tid; idx < 4*16*(VSTR-208); idx += 256) {
        int r = idx / (VSTR-208), c = idx - r*(VSTR-208);
        ((u16*)Ps)[r*VSTR + 208 + c] = 0;
    }
    __syncthreads();

    for (int qt = wave; qt < 13; qt += 4) {
        int q0 = qt*16;
        int qrow = q0 + cb; if (qrow > 195) qrow = 195;   // clamp; stores guarded
        const u16* qp = qkv + base + (size_t)(1 + f*NS + qrow)*(3*DIM);
        short8 a0 = *(const short8*)(qp + quad*8);
        short8 a1 = *(const short8*)(qp + 32 + quad*8);
        // ---- S = Q K^T ----
        f32x4 sacc[13];
        #pragma unroll
        for (int kt = 0; kt < 13; ++kt) {
            int key = kt*16 + cb; if (key > 196) key = 196;
            int ktok = (key == 0) ? 0 : (1 + f*NS + key - 1);
            const u16* kp = qkv + base + (size_t)ktok*(3*DIM) + DIM;
            short8 b0 = *(const short8*)(kp + quad*8);
            short8 b1 = *(const short8*)(kp + 32 + quad*8);
            f32x4 z = {0.f, 0.f, 0.f, 0.f};
            z = __builtin_amdgcn_mfma_f32_16x16x32_bf16(a0, b0, z, 0, 0, 0);
            z = __builtin_amdgcn_mfma_f32_16x16x32_bf16(a1, b1, z, 0, 0, 0);
            sacc[kt] = z;
        }
        // ---- softmax (C layout: col = kt*16+cb, row = quad*4+r) ----
        bool last_ok = (cb < 5);   // key 192+cb < 197
        float mx[4] = {-1e30f, -1e30f, -1e30f, -1e30f};
        #pragma unroll
        for (int kt = 0; kt < 13; ++kt) {
            bool ok = (kt < 12) || last_ok;
            #pragma unroll
            for (int r = 0; r < 4; ++r) {
                float v = sacc[kt][r] * 0.125f;
                sacc[kt][r] = v;
                if (ok) mx[r] = fmaxf(mx[r], v);
            }
        }
        #pragma unroll
        for (int off = 1; off < 16; off <<= 1)
            #pragma unroll
            for (int r = 0; r < 4; ++r)
                mx[r] = fmaxf(mx[r], __shfl_xor(mx[r], off, 64));
        float sum[4] = {0.f, 0.f, 0.f, 0.f};
        u16* prow = &Ps[wave][0];
        #pragma unroll
        for (int kt = 0; kt < 13; ++kt) {
            bool ok = (kt < 12) || last_ok;
            #pragma unroll
            for (int r = 0; r < 4; ++r) {
                float e = ok ? __expf(sacc[kt][r] - mx[r]) : 0.f;
                sum[r] += e;
                prow[(quad*4 + r)*VSTR + kt*16 + cb] = f2bf(e);
            }
        }
        #pragma unroll
        for (int off = 1; off < 16; off <<= 1)
            #pragma unroll
            for (int r = 0; r < 4; ++r)
                sum[r] += __shfl_xor(sum[r], off, 64);
        // ---- O = P V  (A-frag from Ps, B-frag from VT) ----
        short8 pf[7];
        #pragma unroll
        for (int ks = 0; ks < 7; ++ks)
            pf[ks] = *(const short8*)&Ps[wave][cb*VSTR + ks*32 + quad*8];
        f32x4 oacc[4];
        #pragma unroll
        for (int nt = 0; nt < 4; ++nt) {
            f32x4 z = {0.f, 0.f, 0.f, 0.f};
            #pragma unroll
            for (int ks = 0; ks < 7; ++ks) {
                short8 vf = *(const short8*)&VT[(nt*16 + cb)*VSTR + ks*32 + quad*8];
                z = __builtin_amdgcn_mfma_f32_16x16x32_bf16(pf[ks], vf, z, 0, 0, 0);
            }
            oacc[nt] = z;
        }
        float inv[4];
        #pragma unroll
        for (int r = 0; r < 4; ++r) inv[r] = 1.0f / sum[r];
        #pragma unroll
        for (int r = 0; r < 4; ++r) {
            int qr = q0 + quad*4 + r;
            if (qr < 196) {
                size_t orow = ((size_t)b*NT + 1 + (size_t)f*NS + qr)*DIM + (size_t)h*HD;
                #pragma unroll
                for (int nt = 0; nt < 4; ++nt)
                    out[orow + nt*16 + cb] = f2bf(oacc[nt][r] * inv[r]);
            }
        }
    }
}

// ---------------------------------------------------------------------------
extern "C" void kernel_launch(void* const* d_in, const int* in_sizes, int n_in,
                              void* d_out, int out_size, void* d_ws, size_t ws_size,
                              hipStream_t stream) {
    const float* x          = (const float*)d_in[0];
    const float* norm1_w    = (const float*)d_in[1];
    const float* norm1_b    = (const float*)d_in[2];
    const float* norm2_w    = (const float*)d_in[3];
    const float* norm2_b    = (const float*)d_in[4];
    const float* norm3_w    = (const float*)d_in[5];
    const float* norm3_b    = (const float*)d_in[6];
    const float* t_qkv_w    = (const float*)d_in[7];
    const float* t_qkv_b    = (const float*)d_in[8];
    const float* t_proj_w   = (const float*)d_in[9];
    const float* t_proj_b   = (const float*)d_in[10];
    const float* s_qkv_w    = (const float*)d_in[11];
    const float* s_qkv_b    = (const float*)d_in[12];
    const float* s_proj_w   = (const float*)d_in[13];
    const float* s_proj_b   = (const float*)d_in[14];
    const float* mlp_w1     = (const float*)d_in[15];
    const float* mlp_b1     = (const float*)d_in[16];
    const float* mlp_w2     = (const float*)d_in[17];
    const float* mlp_b2     = (const float*)d_in[18];
    float* out = (float*)d_out;

    // workspace layout (bytes)
    char* ws = (char*)d_ws;
    const size_t M = MROWS;
    u16*  qkv  = (u16*)(ws);                          // M*2304 bf16
    u16*  attn = (u16*)(ws + M*2304*2);               // M*768 bf16
    u16*  hbuf = (u16*)(ws);                          // M*3072 bf16 (overlays qkv+attn)
    u16*  xn   = (u16*)(ws + M*3072*2);               // M*768 bf16
    float* x1  = (float*)(ws + M*3072*2 + M*768*2);   // M*768 fp32
    char* wsp  = ws + M*3072*2 + M*768*2 + M*768*4;
    u16* wqT_t = (u16*)(wsp);                 wsp += 2304*768*2;
    u16* wqT_s = (u16*)(wsp);                 wsp += 2304*768*2;
    u16* wpT_t = (u16*)(wsp);                 wsp += 768*768*2;
    u16* wpT_s = (u16*)(wsp);                 wsp += 768*768*2;
    u16* w1T   = (u16*)(wsp);                 wsp += 3072*768*2;
    u16* w2T   = (u16*)(wsp);

    // ---- weight conversion (transpose to [N,K] bf16) ----
    wconv_kernel<<<dim3(2304/32, 768/32), 256, 0, stream>>>(t_qkv_w, wqT_t, 768, 2304);
    wconv_kernel<<<dim3(2304/32, 768/32), 256, 0, stream>>>(s_qkv_w, wqT_s, 768, 2304);
    wconv_kernel<<<dim3(768/32, 768/32), 256, 0, stream>>>(t_proj_w, wpT_t, 768, 768);
    wconv_kernel<<<dim3(768/32, 768/32), 256, 0, stream>>>(s_proj_w, wpT_s, 768, 768);
    wconv_kernel<<<dim3(3072/32, 768/32), 256, 0, stream>>>(mlp_w1, w1T, 768, 3072);
    wconv_kernel<<<dim3(768/32, 3072/32), 256, 0, stream>>>(mlp_w2, w2T, 3072, 768);

    const int GM = (MROWS + 127) / 128;   // 197

    // ---- time attention branch ----
    ln_kernel<<<MROWS, 256, 0, stream>>>(x, norm3_w, norm3_b, xn);
    gemm_kernel<0, true ><<<dim3(GM, 2304/128), 256, 0, stream>>>(xn, wqT_t, t_qkv_b, nullptr, qkv, MROWS, 2304, 768);
    attn_cls_kernel <<<BB*NH, 256, 0, stream>>>(qkv, attn);
    attn_time_kernel<<<BB*NH*NS, 256, 0, stream>>>(qkv, attn);
    gemm_kernel<1, false><<<dim3(GM, 768/128), 256, 0, stream>>>(attn, wpT_t, t_proj_b, x, x1, MROWS, 768, 768);

    // ---- space attention branch ----
    ln_kernel<<<MROWS, 256, 0, stream>>>(x1, norm1_w, norm1_b, xn);
    gemm_kernel<0, true ><<<dim3(GM, 2304/128), 256, 0, stream>>>(xn, wqT_s, s_qkv_b, nullptr, qkv, MROWS, 2304, 768);
    attn_cls_kernel  <<<BB*NH, 256, 0, stream>>>(qkv, attn);
    attn_space_kernel<<<BB*NH*FR, 256, 0, stream>>>(qkv, attn);
    gemm_kernel<1, false><<<dim3(GM, 768/128), 256, 0, stream>>>(attn, wpT_s, s_proj_b, x1, out, MROWS, 768, 768);

    // ---- MLP ----
    ln_kernel<<<MROWS, 256, 0, stream>>>(out, norm2_w, norm2_b, xn);
    gemm_kernel<2, true ><<<dim3(GM, 3072/128), 256, 0, stream>>>(xn, w1T, mlp_b1, nullptr, hbuf, MROWS, 3072, 768);
    gemm_kernel<1, false><<<dim3(GM, 768/128), 256, 0, stream>>>(hbuf, w2T, mlp_b2, out, out, MROWS, 768, 3072);
}

// Round 3
// 1560.176 us; speedup vs baseline: 2.1410x; 1.1184x over previous
//
#include <hip/hip_runtime.h>
#include <cstdint>
#include <cstddef>

typedef unsigned short u16;
typedef __attribute__((ext_vector_type(8))) short short8;
typedef __attribute__((ext_vector_type(4))) float f32x4;

#define BB 16
#define NT 1569
#define DIM 768
#define NH 12
#define HD 64
#define FR 8
#define NS 196
#define MROWS (BB*NT)   // 25104
#define NKEY 197

__device__ __forceinline__ float bf2f(u16 h) {
    return __uint_as_float(((unsigned int)h) << 16);
}
__device__ __forceinline__ u16 f2bf(float f) {
    unsigned int u = __float_as_uint(f);
    u += 0x7fff + ((u >> 16) & 1);   // RNE
    return (u16)(u >> 16);
}
__device__ __forceinline__ void gload_lds16(const u16* g, u16* l) {
    __builtin_amdgcn_global_load_lds(
        (const __attribute__((address_space(1))) void*)g,
        (__attribute__((address_space(3))) void*)l, 16, 0, 0);
}

// ---------------- LayerNorm: fp32/bf16 in -> bf16 out ----------------
template<bool IBF>
__global__ __launch_bounds__(256) void ln_kernel(const void* __restrict__ xin,
        const float* __restrict__ w, const float* __restrict__ b,
        u16* __restrict__ out) {
    int row = blockIdx.x;
    size_t base = (size_t)row * DIM;
    int tid = threadIdx.x;
    float v0, v1, v2;
    if (IBF) {
        const u16* x = (const u16*)xin;
        v0 = bf2f(x[base + tid]); v1 = bf2f(x[base + tid + 256]); v2 = bf2f(x[base + tid + 512]);
    } else {
        const float* x = (const float*)xin;
        v0 = x[base + tid]; v1 = x[base + tid + 256]; v2 = x[base + tid + 512];
    }
    float s = v0 + v1 + v2;
    float q = v0*v0 + v1*v1 + v2*v2;
    #pragma unroll
    for (int o = 32; o >= 1; o >>= 1) {
        s += __shfl_xor(s, o, 64);
        q += __shfl_xor(q, o, 64);
    }
    __shared__ float rs[4], rq[4];
    int wave = tid >> 6, lane = tid & 63;
    if (lane == 0) { rs[wave] = s; rq[wave] = q; }
    __syncthreads();
    float S = rs[0]+rs[1]+rs[2]+rs[3];
    float Q = rq[0]+rq[1]+rq[2]+rq[3];
    float mean = S * (1.0f/DIM);
    float var  = Q * (1.0f/DIM) - mean*mean;
    float inv  = rsqrtf(var + 1e-6f);
    out[base+tid]     = f2bf((v0-mean)*inv*w[tid]     + b[tid]);
    out[base+tid+256] = f2bf((v1-mean)*inv*w[tid+256] + b[tid+256]);
    out[base+tid+512] = f2bf((v2-mean)*inv*w[tid+512] + b[tid+512]);
}

// ------------- weight convert: fp32 [K,N] -> bf16 [N,K] -------------
__global__ __launch_bounds__(256) void wconv_kernel(const float* __restrict__ in,
        u16* __restrict__ out, int K, int N) {
    __shared__ float tile[32][33];
    int n0 = blockIdx.x * 32, k0 = blockIdx.y * 32;
    int tx = threadIdx.x & 31, ty = threadIdx.x >> 5;
    #pragma unroll
    for (int i = 0; i < 32; i += 8)
        tile[ty+i][tx] = in[(size_t)(k0+ty+i)*N + n0+tx];
    __syncthreads();
    #pragma unroll
    for (int i = 0; i < 32; i += 8)
        out[(size_t)(n0+ty+i)*K + k0+tx] = f2bf(tile[tx][ty+i]);
}

// ---------------- bf16 MFMA GEMM: C = A[M,K] * BT[N,K]^T ----------------
// EPI: 0=+bias, 1=+bias+residual, 2=+bias+gelu. OBF: bf16 out. RBF: bf16 resid.
// global_load_lds width-16 staging (m97 pattern); grouped-pid swizzle (GROUP_M=16)
// for L3/L2 A-stripe reuse across column blocks.
template<int EPI, bool OBF, bool RBF>
__global__ __launch_bounds__(256) void gemm_kernel(
        const u16* __restrict__ A, const u16* __restrict__ BT,
        const float* __restrict__ bias, const void* __restrict__ resid,
        void* __restrict__ Cout, int M, int N, int K, int num_m, int num_n) {
    __shared__ u16 lsA[128*32];    // unpadded: forced by global_load_lds lane mapping
    __shared__ u16 lsB[128*32];
    // grouped pid mapping (Triton GROUP_M style)
    const int GRP = 16;
    int pid = blockIdx.x;
    int gsz = GRP * num_n;
    int gid = pid / gsz;
    int rem = pid - gid*gsz;
    int m0b = gid * GRP;
    int msz = num_m - m0b; if (msz > GRP) msz = GRP;
    int pm = m0b + rem % msz;
    int pn = rem / msz;
    int row0 = pm * 128, col0 = pn * 128;
    int tid = threadIdx.x;
    int wave = tid >> 6, lane = tid & 63;
    int wm = (wave >> 1) * 64, wn = (wave & 1) * 64;
    int lrow = lane & 15, quad = lane >> 4;
    // staging: wave w instr i covers rows w*32+i*16..+16; lane l -> row+l/4, col (l%4)*8
    int srow = lane >> 2, scol = (lane & 3) * 8;
    const u16* gAp[2]; const u16* gBp[2];
    u16* lA[2]; u16* lB[2];
    #pragma unroll
    for (int i = 0; i < 2; ++i) {
        int r = wave*32 + i*16 + srow;
        int gr = row0 + r; if (gr > M-1) gr = M-1;   // clamp; stores guarded
        gAp[i] = A  + (size_t)gr*K + scol;
        gBp[i] = BT + (size_t)(col0 + r)*K + scol;
        lA[i] = &lsA[(wave*32 + i*16)*32];
        lB[i] = &lsB[(wave*32 + i*16)*32];
    }
    f32x4 acc[4][4] = {};
    for (int k0 = 0; k0 < K; k0 += 32) {
        #pragma unroll
        for (int i = 0; i < 2; ++i) {
            gload_lds16(gAp[i] + k0, lA[i]);
            gload_lds16(gBp[i] + k0, lB[i]);
        }
        __syncthreads();
        short8 af[4], bfr[4];
        #pragma unroll
        for (int t = 0; t < 4; ++t)
            af[t] = *(const short8*)&lsA[(wm + t*16 + lrow)*32 + quad*8];
        #pragma unroll
        for (int t = 0; t < 4; ++t)
            bfr[t] = *(const short8*)&lsB[(wn + t*16 + lrow)*32 + quad*8];
        #pragma unroll
        for (int i = 0; i < 4; ++i)
            #pragma unroll
            for (int j = 0; j < 4; ++j)
                acc[i][j] = __builtin_amdgcn_mfma_f32_16x16x32_bf16(af[i], bfr[j], acc[i][j], 0, 0, 0);
        __syncthreads();
    }
    #pragma unroll
    for (int i = 0; i < 4; ++i) {
      #pragma unroll
      for (int j = 0; j < 4; ++j) {
        int gn = col0 + wn + j*16 + lrow;
        float bv = bias[gn];
        #pragma unroll
        for (int r = 0; r < 4; ++r) {
            int gm = row0 + wm + i*16 + quad*4 + r;
            if (gm < M) {
                float v = acc[i][j][r] + bv;
                if (EPI == 1) {
                    size_t ridx = (size_t)gm*N + gn;
                    v += RBF ? bf2f(((const u16*)resid)[ridx]) : ((const float*)resid)[ridx];
                }
                if (EPI == 2) {
                    float z = 0.7978845608028654f*(v + 0.044715f*v*v*v);
                    float t = 1.0f - 2.0f/(__expf(2.0f*z) + 1.0f);   // tanh(z)
                    v = 0.5f*v*(1.0f + t);
                }
                if (OBF) ((u16*)Cout)[(size_t)gm*N + gn] = f2bf(v);
                else     ((float*)Cout)[(size_t)gm*N + gn] = v;
            }
        }
      }
    }
}

// ------------- cls-token global attention: one block per (b,h) -------------
__global__ __launch_bounds__(256) void attn_cls_kernel(const u16* __restrict__ qkv,
        u16* __restrict__ out) {
    __shared__ float s[NT];
    __shared__ float qf[64];
    __shared__ float part[4][64];
    __shared__ float red[4];
    int b = blockIdx.x / NH, h = blockIdx.x % NH;
    size_t base = ((size_t)b*NT)*(3*DIM) + h*HD;
    int tid = threadIdx.x;
    if (tid < 64) qf[tid] = bf2f(qkv[base + tid]);
    __syncthreads();
    float lmax = -1e30f;
    for (int t = tid; t < NT; t += 256) {
        const u16* kp = qkv + base + (size_t)t*(3*DIM) + DIM;
        float a0=0,a1=0,a2=0,a3=0;
        #pragma unroll
        for (int d = 0; d < 64; d += 4) {
            a0 += qf[d]  *bf2f(kp[d]);
            a1 += qf[d+1]*bf2f(kp[d+1]);
            a2 += qf[d+2]*bf2f(kp[d+2]);
            a3 += qf[d+3]*bf2f(kp[d+3]);
        }
        float sc = (a0+a1+a2+a3)*0.125f;
        s[t] = sc;
        lmax = fmaxf(lmax, sc);
    }
    #pragma unroll
    for (int o = 32; o >= 1; o >>= 1) lmax = fmaxf(lmax, __shfl_xor(lmax, o, 64));
    if ((tid&63) == 0) red[tid>>6] = lmax;
    __syncthreads();
    float m = fmaxf(fmaxf(red[0],red[1]), fmaxf(red[2],red[3]));
    float lsum = 0.f;
    for (int t = tid; t < NT; t += 256) { float e = __expf(s[t]-m); s[t] = e; lsum += e; }
    #pragma unroll
    for (int o = 32; o >= 1; o >>= 1) lsum += __shfl_xor(lsum, o, 64);
    __syncthreads();
    if ((tid&63) == 0) red[tid>>6] = lsum;
    __syncthreads();
    float inv = 1.0f/(red[0]+red[1]+red[2]+red[3]);
    int d = tid & 63, g = tid >> 6;
    float a = 0.f;
    for (int t = g; t < NT; t += 4)
        a += s[t]*bf2f(qkv[base + (size_t)t*(3*DIM) + 2*DIM + d]);
    part[g][d] = a;
    __syncthreads();
    if (tid < 64) {
        float o = (part[0][tid]+part[1][tid]+part[2][tid]+part[3][tid])*inv;
        out[((size_t)b*NT)*DIM + h*HD + tid] = f2bf(o);
    }
}

// ------------- time attention: one block per (b,h,n); 8 q x 9 kv -------------
__global__ __launch_bounds__(256) void attn_time_kernel(const u16* __restrict__ qkv,
        u16* __restrict__ out) {
    __shared__ float qs[8][68], ks[9][68], vs[9][68];
    __shared__ float pr[8][12];
    int bid = blockIdx.x;
    int n = bid % NS; int rem = bid / NS; int h = rem % NH; int b = rem / NH;
    size_t base = ((size_t)b*NT)*(3*DIM) + h*HD;
    int tid = threadIdx.x;
    for (int idx = tid; idx < 512; idx += 256) {
        int f = idx >> 6, d = idx & 63;
        int tok = 1 + f*NS + n;
        size_t p = base + (size_t)tok*(3*DIM) + d;
        qs[f][d]   = bf2f(qkv[p]);
        ks[f+1][d] = bf2f(qkv[p + DIM]);
        vs[f+1][d] = bf2f(qkv[p + 2*DIM]);
    }
    if (tid < 64) {
        ks[0][tid] = bf2f(qkv[base + DIM + tid]);
        vs[0][tid] = bf2f(qkv[base + 2*DIM + tid]);
    }
    __syncthreads();
    if (tid < 72) {
        int fq = tid / 9, kk = tid % 9;
        float a0=0,a1=0,a2=0,a3=0;
        #pragma unroll
        for (int d = 0; d < 64; d += 4) {
            a0 += qs[fq][d]  *ks[kk][d];
            a1 += qs[fq][d+1]*ks[kk][d+1];
            a2 += qs[fq][d+2]*ks[kk][d+2];
            a3 += qs[fq][d+3]*ks[kk][d+3];
        }
        pr[fq][kk] = (a0+a1+a2+a3)*0.125f;
    }
    __syncthreads();
    if (tid < 8) {
        float m = -1e30f;
        #pragma unroll
        for (int kk = 0; kk < 9; ++kk) m = fmaxf(m, pr[tid][kk]);
        float sum = 0.f;
        #pragma unroll
        for (int kk = 0; kk < 9; ++kk) { float e = __expf(pr[tid][kk]-m); pr[tid][kk] = e; sum += e; }
        float inv = 1.0f/sum;
        #pragma unroll
        for (int kk = 0; kk < 9; ++kk) pr[tid][kk] *= inv;
    }
    __syncthreads();
    for (int idx = tid; idx < 512; idx += 256) {
        int fq = idx >> 6, d = idx & 63;
        float a = 0.f;
        #pragma unroll
        for (int kk = 0; kk < 9; ++kk) a += pr[fq][kk]*vs[kk][d];
        int tok = 1 + fq*NS + n;
        out[((size_t)b*NT + tok)*DIM + h*HD + d] = f2bf(a);
    }
}

// ------------- space attention (MFMA): one block per (b,h,f) -------------
#define VSTR 232
__global__ __launch_bounds__(256, 2) void attn_space_kernel(const u16* __restrict__ qkv,
        u16* __restrict__ out) {
    __shared__ u16 VT[64*VSTR];        // [d][key], cols 197..231 zero
    __shared__ u16 Ps[4][16*VSTR];     // per-wave P[qrow][key], cols 208..231 zero
    int bid = blockIdx.x;
    int b = bid / (NH*FR); int rem = bid % (NH*FR); int h = rem / FR; int f = rem % FR;
    size_t base = ((size_t)b*NT)*(3*DIM) + (size_t)h*HD;
    int tid = threadIdx.x;
    int wave = tid >> 6, lane = tid & 63;
    int cb = lane & 15, quad = lane >> 4;

    for (int idx = tid; idx < NKEY*64; idx += 256) {
        int d = idx / NKEY, key = idx - d*NKEY;
        int tok = (key == 0) ? 0 : (1 + f*NS + key - 1);
        VT[d*VSTR + key] = qkv[base + (size_t)tok*(3*DIM) + 2*DIM + d];
    }
    for (int idx = tid; idx < 64*(VSTR-NKEY); idx += 256) {
        int d = idx / (VSTR-NKEY), c = idx - d*(VSTR-NKEY);
        VT[d*VSTR + NKEY + c] = 0;
    }
    for (int idx = tid; idx < 4*16*(VSTR-208); idx += 256) {
        int r = idx / (VSTR-208), c = idx - r*(VSTR-208);
        ((u16*)Ps)[r*VSTR + 208 + c] = 0;
    }
    __syncthreads();

    for (int qt = wave; qt < 13; qt += 4) {
        int q0 = qt*16;
        int qrow = q0 + cb; if (qrow > 195) qrow = 195;
        const u16* qp = qkv + base + (size_t)(1 + f*NS + qrow)*(3*DIM);
        short8 a0 = *(const short8*)(qp + quad*8);
        short8 a1 = *(const short8*)(qp + 32 + quad*8);
        f32x4 sacc[13];
        #pragma unroll
        for (int kt = 0; kt < 13; ++kt) {
            int key = kt*16 + cb; if (key > 196) key = 196;
            int ktok = (key == 0) ? 0 : (1 + f*NS + key - 1);
            const u16* kp = qkv + base + (size_t)ktok*(3*DIM) + DIM;
            short8 b0 = *(const short8*)(kp + quad*8);
            short8 b1 = *(const short8*)(kp + 32 + quad*8);
            f32x4 z = {0.f, 0.f, 0.f, 0.f};
            z = __builtin_amdgcn_mfma_f32_16x16x32_bf16(a0, b0, z, 0, 0, 0);
            z = __builtin_amdgcn_mfma_f32_16x16x32_bf16(a1, b1, z, 0, 0, 0);
            sacc[kt] = z;
        }
        bool last_ok = (cb < 5);
        float mx[4] = {-1e30f, -1e30f, -1e30f, -1e30f};
        #pragma unroll
        for (int kt = 0; kt < 13; ++kt) {
            bool ok = (kt < 12) || last_ok;
            #pragma unroll
            for (int r = 0; r < 4; ++r) {
                float v = sacc[kt][r] * 0.125f;
                sacc[kt][r] = v;
                if (ok) mx[r] = fmaxf(mx[r], v);
            }
        }
        #pragma unroll
        for (int off = 1; off < 16; off <<= 1)
            #pragma unroll
            for (int r = 0; r < 4; ++r)
                mx[r] = fmaxf(mx[r], __shfl_xor(mx[r], off, 64));
        float sum[4] = {0.f, 0.f, 0.f, 0.f};
        u16* prow = &Ps[wave][0];
        #pragma unroll
        for (int kt = 0; kt < 13; ++kt) {
            bool ok = (kt < 12) || last_ok;
            #pragma unroll
            for (int r = 0; r < 4; ++r) {
                float e = ok ? __expf(sacc[kt][r] - mx[r]) : 0.f;
                sum[r] += e;
                prow[(quad*4 + r)*VSTR + kt*16 + cb] = f2bf(e);
            }
        }
        #pragma unroll
        for (int off = 1; off < 16; off <<= 1)
            #pragma unroll
            for (int r = 0; r < 4; ++r)
                sum[r] += __shfl_xor(sum[r], off, 64);
        short8 pf[7];
        #pragma unroll
        for (int ks = 0; ks < 7; ++ks)
            pf[ks] = *(const short8*)&Ps[wave][cb*VSTR + ks*32 + quad*8];
        f32x4 oacc[4];
        #pragma unroll
        for (int nt = 0; nt < 4; ++nt) {
            f32x4 z = {0.f, 0.f, 0.f, 0.f};
            #pragma unroll
            for (int ks = 0; ks < 7; ++ks) {
                short8 vf = *(const short8*)&VT[(nt*16 + cb)*VSTR + ks*32 + quad*8];
                z = __builtin_amdgcn_mfma_f32_16x16x32_bf16(pf[ks], vf, z, 0, 0, 0);
            }
            oacc[nt] = z;
        }
        float inv[4];
        #pragma unroll
        for (int r = 0; r < 4; ++r) inv[r] = 1.0f / sum[r];
        #pragma unroll
        for (int r = 0; r < 4; ++r) {
            int qr = q0 + quad*4 + r;
            if (qr < 196) {
                size_t orow = ((size_t)b*NT + 1 + (size_t)f*NS + qr)*DIM + (size_t)h*HD;
                #pragma unroll
                for (int nt = 0; nt < 4; ++nt)
                    out[orow + nt*16 + cb] = f2bf(oacc[nt][r] * inv[r]);
            }
        }
    }
}

// ---------------------------------------------------------------------------
extern "C" void kernel_launch(void* const* d_in, const int* in_sizes, int n_in,
                              void* d_out, int out_size, void* d_ws, size_t ws_size,
                              hipStream_t stream) {
    const float* x          = (const float*)d_in[0];
    const float* norm1_w    = (const float*)d_in[1];
    const float* norm1_b    = (const float*)d_in[2];
    const float* norm2_w    = (const float*)d_in[3];
    const float* norm2_b    = (const float*)d_in[4];
    const float* norm3_w    = (const float*)d_in[5];
    const float* norm3_b    = (const float*)d_in[6];
    const float* t_qkv_w    = (const float*)d_in[7];
    const float* t_qkv_b    = (const float*)d_in[8];
    const float* t_proj_w   = (const float*)d_in[9];
    const float* t_proj_b   = (const float*)d_in[10];
    const float* s_qkv_w    = (const float*)d_in[11];
    const float* s_qkv_b    = (const float*)d_in[12];
    const float* s_proj_w   = (const float*)d_in[13];
    const float* s_proj_b   = (const float*)d_in[14];
    const float* mlp_w1     = (const float*)d_in[15];
    const float* mlp_b1     = (const float*)d_in[16];
    const float* mlp_w2     = (const float*)d_in[17];
    const float* mlp_b2     = (const float*)d_in[18];
    float* out = (float*)d_out;

    // workspace layout (bytes)
    char* ws = (char*)d_ws;
    const size_t M = MROWS;
    u16*  qkv  = (u16*)(ws);                          // M*2304 bf16
    u16*  attn = (u16*)(ws + M*2304*2);               // M*768 bf16
    u16*  hbuf = (u16*)(ws);                          // M*3072 bf16 (overlays qkv+attn)
    u16*  xn   = (u16*)(ws + M*3072*2);               // M*768 bf16
    u16*  x1   = (u16*)(ws + M*3072*2 + M*768*2);     // M*768 bf16 (t-branch residual)
    char* wsp  = ws + M*3072*2 + M*768*2 + M*768*4;
    u16* wqT_t = (u16*)(wsp);                 wsp += 2304*768*2;
    u16* wqT_s = (u16*)(wsp);                 wsp += 2304*768*2;
    u16* wpT_t = (u16*)(wsp);                 wsp += 768*768*2;
    u16* wpT_s = (u16*)(wsp);                 wsp += 768*768*2;
    u16* w1T   = (u16*)(wsp);                 wsp += 3072*768*2;
    u16* w2T   = (u16*)(wsp);

    // ---- weight conversion (transpose to [N,K] bf16) ----
    wconv_kernel<<<dim3(2304/32, 768/32), 256, 0, stream>>>(t_qkv_w, wqT_t, 768, 2304);
    wconv_kernel<<<dim3(2304/32, 768/32), 256, 0, stream>>>(s_qkv_w, wqT_s, 768, 2304);
    wconv_kernel<<<dim3(768/32, 768/32), 256, 0, stream>>>(t_proj_w, wpT_t, 768, 768);
    wconv_kernel<<<dim3(768/32, 768/32), 256, 0, stream>>>(s_proj_w, wpT_s, 768, 768);
    wconv_kernel<<<dim3(3072/32, 768/32), 256, 0, stream>>>(mlp_w1, w1T, 768, 3072);
    wconv_kernel<<<dim3(768/32, 3072/32), 256, 0, stream>>>(mlp_w2, w2T, 3072, 768);

    const int GM = (MROWS + 127) / 128;   // 197

    // ---- time attention branch ----
    ln_kernel<false><<<MROWS, 256, 0, stream>>>(x, norm3_w, norm3_b, xn);
    gemm_kernel<0, true, false><<<GM*(2304/128), 256, 0, stream>>>(xn, wqT_t, t_qkv_b, nullptr, qkv, MROWS, 2304, 768, GM, 2304/128);
    attn_cls_kernel <<<BB*NH, 256, 0, stream>>>(qkv, attn);
    attn_time_kernel<<<BB*NH*NS, 256, 0, stream>>>(qkv, attn);
    gemm_kernel<1, true, false><<<GM*(768/128), 256, 0, stream>>>(attn, wpT_t, t_proj_b, x, x1, MROWS, 768, 768, GM, 768/128);

    // ---- space attention branch ----
    ln_kernel<true><<<MROWS, 256, 0, stream>>>(x1, norm1_w, norm1_b, xn);
    gemm_kernel<0, true, false><<<GM*(2304/128), 256, 0, stream>>>(xn, wqT_s, s_qkv_b, nullptr, qkv, MROWS, 2304, 768, GM, 2304/128);
    attn_cls_kernel  <<<BB*NH, 256, 0, stream>>>(qkv, attn);
    attn_space_kernel<<<BB*NH*FR, 256, 0, stream>>>(qkv, attn);
    gemm_kernel<1, false, true><<<GM*(768/128), 256, 0, stream>>>(attn, wpT_s, s_proj_b, x1, out, MROWS, 768, 768, GM, 768/128);

    // ---- MLP ----
    ln_kernel<false><<<MROWS, 256, 0, stream>>>(out, norm2_w, norm2_b, xn);
    gemm_kernel<2, true, false><<<GM*(3072/128), 256, 0, stream>>>(xn, w1T, mlp_b1, nullptr, hbuf, MROWS, 3072, 768, GM, 3072/128);
    gemm_kernel<1, false, false><<<GM*(768/128), 256, 0, stream>>>(hbuf, w2T, mlp_b2, out, out, MROWS, 768, 3072, GM, 768/128);
}